// Round 4
// baseline (45.546 us; speedup 1.0000x reference)
//
#include <hip/hip_runtime.h>

// VQ codebook search via bf16 MFMA — codebook-in-VGPR version.
// latents: [32, 64, 64, 64] = [b, d, h, w] fp32
// emb:     [512, 64] fp32
// out:     8388608 floats quantized (b,d,h,w) + 1 float vq_loss
//
// score[n,k] = ||e_k||^2 - 2 x_n.e_k  (||x||^2 argmin-invariant), MFMA 16x16x32:
// A = bf16(-2E) [16 codes x 32 d] held in VGPRs (wave w owns codes [w*64,w*64+64)),
// B = bf16(X) [32 d x 16 px] from swizzled LDS, C-init = e2 => D = score.
//
// ws layout (floats): [0..512) per-block loss partials; [512..1024) e2;
//   ws+1024: ebf2 = bf16(-2E) as [2 halves][512 codes][32 d], 64KB total.

typedef short short8v __attribute__((ext_vector_type(8)));
typedef float f32x4   __attribute__((ext_vector_type(4)));

constexpr int K = 512;
constexpr int D = 64;
constexpr int HW = 4096;
constexpr int NPIX = 32 * HW;
constexpr long long NELEM = (long long)NPIX * D;
constexpr int PXB = 256;                 // pixels per block
constexpr int NBLK = NPIX / PXB;         // 512 blocks

__device__ inline unsigned short f2bf(float f) {   // RNE float->bf16 bits
    unsigned int u = __builtin_bit_cast(unsigned int, f);
    u += 0x7fffu + ((u >> 16) & 1u);
    return (unsigned short)(u >> 16);
}

// ---- prep: e2[k] = ||e_k||^2 fp32; ebf2[h][k][j] = bf16(-2*emb[k][h*32+j]).
__global__ __launch_bounds__(256) void vq_prep(const float* __restrict__ emb,
                                               float* __restrict__ e2,
                                               unsigned short* __restrict__ ebf2) {
    int tid = blockIdx.x * 256 + threadIdx.x;    // 0..8191 = k*4 + quad (quad = 16 d's)
    int k = tid >> 2, quad = tid & 3;
    const float4* src = reinterpret_cast<const float4*>(emb + k * D + quad * 16);
    unsigned int pk[8];
    float s = 0.f;
    #pragma unroll
    for (int i = 0; i < 4; ++i) {
        float4 v = src[i];
        s = fmaf(v.x, v.x, fmaf(v.y, v.y, fmaf(v.z, v.z, fmaf(v.w, v.w, s))));
        pk[2*i]   = (unsigned int)f2bf(-2.f * v.x) | ((unsigned int)f2bf(-2.f * v.y) << 16);
        pk[2*i+1] = (unsigned int)f2bf(-2.f * v.z) | ((unsigned int)f2bf(-2.f * v.w) << 16);
    }
    s += __shfl_xor(s, 1, 64);                   // reduce over the 4 quads of row k
    s += __shfl_xor(s, 2, 64);
    if (quad == 0) e2[k] = s;
    // quad 0,1 -> half 0 (d 0..31); quad 2,3 -> half 1 (d 32..63)
    int h = quad >> 1, jb = (quad & 1) * 16;
    unsigned int* dst = reinterpret_cast<unsigned int*>(ebf2 + h * (K * 32) + k * 32 + jb);
    *reinterpret_cast<uint4*>(dst)     = uint4{pk[0], pk[1], pk[2], pk[3]};
    *reinterpret_cast<uint4*>(dst + 4) = uint4{pk[4], pk[5], pk[6], pk[7]};
}

// ---- main: 512 blocks x 512 threads; 256 px/block; codes split across waves.
__global__ __launch_bounds__(512) void vq_main(const float* __restrict__ latents,
                                               const float* __restrict__ emb,
                                               const float* __restrict__ e2,
                                               const unsigned short* __restrict__ ebf2,
                                               float* __restrict__ out,
                                               float* __restrict__ partials) {
    __shared__ unsigned short xbf[PXB * D];      // 32KB, row=pixel, XOR-swizzled
    __shared__ float          sred[8][PXB];      // 8KB  per-wave best score
    __shared__ unsigned short cred[8][PXB];      // 4KB  per-wave best code
    __shared__ int            inds[PXB];         // 1KB
    __shared__ float          wsum[8];

    const int t    = threadIdx.x;
    const int lane = t & 63, w = t >> 6;         // 8 waves
    const int blk  = blockIdx.x;
    const int b    = blk >> 4, hw0 = (blk & 15) * PXB;
    const int r15  = lane & 15, g = lane >> 4;

    // ---- stage x: thread t owns pixel px, dims [dbase, dbase+32). HBM coalesced.
    const int px = t & 255;
    const int dbase = (t >> 8) * 32;
    const float* __restrict__ xg = latents + (size_t)b * D * HW + hw0 + px;
    float xv[32];
    #pragma unroll
    for (int j = 0; j < 32; ++j) xv[j] = xg[(size_t)(dbase + j) * HW];

    // ---- load this wave's codebook slice into VGPRs (L2/L3-resident, once).
    // Wave w owns codes [w*64, w*64+64) = 4 tiles. A-frag: row=r15, k-chunk=g.
    short8v A0[4], A1[4];
    f32x4   EI[4];
    {
        const char* eb = reinterpret_cast<const char*>(ebf2);
        #pragma unroll
        for (int tt = 0; tt < 4; ++tt) {
            int code = w * 64 + tt * 16 + r15;
            A0[tt] = *reinterpret_cast<const short8v*>(eb + (size_t)code * 64 + g * 16);
            A1[tt] = *reinterpret_cast<const short8v*>(eb + (size_t)(K * 64) + (size_t)code * 64 + g * 16);
            EI[tt] = *reinterpret_cast<const f32x4*>(e2 + w * 64 + tt * 16 + g * 4);
        }
    }

    // ---- pack x to bf16, write swizzled (row=px): 4x ds_write_b128.
    char* xb_c = reinterpret_cast<char*>(xbf);
    {
        const int pswz = (px & 7) << 4;
        #pragma unroll
        for (int ch = 0; ch < 4; ++ch) {
            unsigned int pk[4];
            #pragma unroll
            for (int q = 0; q < 4; ++q) {
                int j = ch * 8 + q * 2;
                pk[q] = (unsigned int)f2bf(xv[j]) | ((unsigned int)f2bf(xv[j + 1]) << 16);
            }
            int col = dbase * 2 + ch * 16;
            *reinterpret_cast<uint4*>(xb_c + px * 128 + (col ^ pswz)) = uint4{pk[0], pk[1], pk[2], pk[3]};
        }
    }
    __syncthreads();

    // ---- k-loop: every wave scans ALL 16 pixel-tiles against its 64 codes.
    #pragma unroll 4
    for (int pt = 0; pt < 16; ++pt) {
        const int P = pt * 16 + r15;
        const int sw = (P & 7) << 4;
        short8v b0 = *reinterpret_cast<const short8v*>(xb_c + P * 128 + ((g * 16)      ^ sw));
        short8v b1 = *reinterpret_cast<const short8v*>(xb_c + P * 128 + ((g * 16 + 64) ^ sw));
        float bs = 3.4e38f;
        int   bc = 0;
        #pragma unroll
        for (int tt = 0; tt < 4; ++tt) {
            f32x4 c = EI[tt];                    // C-in = e2 => D = score
            c = __builtin_amdgcn_mfma_f32_16x16x32_bf16(A0[tt], b0, c, 0, 0, 0);
            c = __builtin_amdgcn_mfma_f32_16x16x32_bf16(A1[tt], b1, c, 0, 0, 0);
            #pragma unroll
            for (int el = 0; el < 4; ++el) {     // ascending (tt,el) + strict < = first-min
                float s = c[el];
                if (s < bs) { bs = s; bc = tt * 16 + g * 4 + el; }
            }
        }
        // reduce across the 4 g-groups sharing pixel P (lex: score, then code)
        #pragma unroll
        for (int off = 16; off < 64; off <<= 1) {
            float os = __shfl_xor(bs, off, 64);
            int   oc = __shfl_xor(bc, off, 64);
            if (os < bs || (os == bs && oc < bc)) { bs = os; bc = oc; }
        }
        if (g == 0) { sred[w][P] = bs; cred[w][P] = (unsigned short)(w * 64 + bc); }
    }
    __syncthreads();

    // ---- cross-wave argmin (ascending wave => ascending code range; strict <).
    if (t < PXB) {
        float bs = sred[0][t];
        int   bc = cred[0][t];
        #pragma unroll
        for (int wv = 1; wv < 8; ++wv) {
            float s = sred[wv][t];
            int   c2 = cred[wv][t];
            if (s < bs) { bs = s; bc = c2; }
        }
        inds[t] = bc;
    }
    __syncthreads();

    // ---- epilogue: x in regs; gather chosen code fp32 (L2), write out, loss.
    const int ind = inds[px];
    const float4* __restrict__ q4 = reinterpret_cast<const float4*>(emb + ind * D + dbase);
    float* __restrict__ og = out + (size_t)b * D * HW + hw0 + px;
    float lsum = 0.f;
    #pragma unroll
    for (int i = 0; i < 8; ++i) {
        float4 q = q4[i];
        int j = 4 * i;
        float f0 = q.x - xv[j + 0];
        float f1 = q.y - xv[j + 1];
        float f2 = q.z - xv[j + 2];
        float f3 = q.w - xv[j + 3];
        lsum = fmaf(f0, f0, lsum); lsum = fmaf(f1, f1, lsum);
        lsum = fmaf(f2, f2, lsum); lsum = fmaf(f3, f3, lsum);
        og[(size_t)(dbase + j + 0) * HW] = q.x;
        og[(size_t)(dbase + j + 1) * HW] = q.y;
        og[(size_t)(dbase + j + 2) * HW] = q.z;
        og[(size_t)(dbase + j + 3) * HW] = q.w;
    }
    #pragma unroll
    for (int off = 32; off > 0; off >>= 1) lsum += __shfl_down(lsum, off, 64);
    if (lane == 0) wsum[w] = lsum;
    __syncthreads();
    if (t == 0) {
        float s = 0.f;
        #pragma unroll
        for (int i = 0; i < 8; ++i) s += wsum[i];
        partials[blk] = s;
    }
}

__global__ __launch_bounds__(512) void vq_finalize(const float* __restrict__ partials,
                                                   float* __restrict__ out_loss) {
    int t = threadIdx.x;
    float v = partials[t];
    #pragma unroll
    for (int off = 32; off > 0; off >>= 1) v += __shfl_down(v, off, 64);
    __shared__ float s8[8];
    if ((t & 63) == 0) s8[t >> 6] = v;
    __syncthreads();
    if (t == 0) {
        float tot = 0.f;
        #pragma unroll
        for (int i = 0; i < 8; ++i) tot += s8[i];
        out_loss[0] = 1.25f * tot / (float)NELEM;   // beta*commit + embed (equal values)
    }
}

extern "C" void kernel_launch(void* const* d_in, const int* in_sizes, int n_in,
                              void* d_out, int out_size, void* d_ws, size_t ws_size,
                              hipStream_t stream) {
    const float* latents = (const float*)d_in[0];
    const float* emb     = (const float*)d_in[1];
    float* out = (float*)d_out;
    float* ws  = (float*)d_ws;

    float*          part = ws;                               // [0..512)
    float*          e2   = ws + 512;                         // [512..1024)
    unsigned short* ebf2 = (unsigned short*)(ws + 1024);     // 64KB

    vq_prep<<<32, 256, 0, stream>>>(emb, e2, ebf2);
    vq_main<<<NBLK, 512, 0, stream>>>(latents, emb, e2, ebf2, out, part);
    vq_finalize<<<1, 512, 0, stream>>>(part, out + NELEM);
}

// Round 5
// 33.591 us; speedup vs baseline: 1.3559x; 1.3559x over previous
//
#include <hip/hip_runtime.h>

// VQ codebook search via bf16 MFMA — codebook-in-VGPR, spill-free version.
// latents: [32, 64, 64, 64] = [b, d, h, w] fp32
// emb:     [512, 64] fp32
// out:     8388608 floats quantized (b,d,h,w) + 1 float vq_loss
//
// score[n,k] = ||e_k||^2 - 2 x_n.e_k, MFMA 16x16x32 (A = bf16(-2E) in VGPRs,
// wave w owns codes [w*64,w*64+64); B = bf16(X) from swizzled LDS; C-init = e2).
// argmin via u32 key = (int(score*2^21 + 2^20) << 9) | code  (min = lex order).
// loss identity: ||q-x||^2 = ||x||^2 + score  -> no x liveness past staging.
//
// ws layout (floats): [0..1024) per-block loss partials; [1024..1536) e2;
//   ws+1536: ebf2 = bf16(-2E) as [2 halves][512 codes][32 d], 64KB.

typedef short short8v __attribute__((ext_vector_type(8)));
typedef float f32x4   __attribute__((ext_vector_type(4)));

constexpr int K = 512;
constexpr int D = 64;
constexpr int HW = 4096;
constexpr int NPIX = 32 * HW;
constexpr long long NELEM = (long long)NPIX * D;
constexpr int PXB = 128;                 // pixels per block
constexpr int NBLK = NPIX / PXB;         // 1024 blocks

__device__ inline unsigned short f2bf(float f) {   // RNE float->bf16 bits
    unsigned int u = __builtin_bit_cast(unsigned int, f);
    u += 0x7fffu + ((u >> 16) & 1u);
    return (unsigned short)(u >> 16);
}

// ---- prep: e2[k] = ||e_k||^2 fp32; ebf2[h][k][j] = bf16(-2*emb[k][h*32+j]).
__global__ __launch_bounds__(256) void vq_prep(const float* __restrict__ emb,
                                               float* __restrict__ e2,
                                               unsigned short* __restrict__ ebf2) {
    int tid = blockIdx.x * 256 + threadIdx.x;    // 0..8191 = k*4 + quad (16 d's each)
    int k = tid >> 2, quad = tid & 3;
    const float4* src = reinterpret_cast<const float4*>(emb + k * D + quad * 16);
    unsigned int pk[8];
    float s = 0.f;
    #pragma unroll
    for (int i = 0; i < 4; ++i) {
        float4 v = src[i];
        s = fmaf(v.x, v.x, fmaf(v.y, v.y, fmaf(v.z, v.z, fmaf(v.w, v.w, s))));
        pk[2*i]   = (unsigned int)f2bf(-2.f * v.x) | ((unsigned int)f2bf(-2.f * v.y) << 16);
        pk[2*i+1] = (unsigned int)f2bf(-2.f * v.z) | ((unsigned int)f2bf(-2.f * v.w) << 16);
    }
    s += __shfl_xor(s, 1, 64);                   // reduce over the 4 quads of row k
    s += __shfl_xor(s, 2, 64);
    if (quad == 0) e2[k] = s;
    int h = quad >> 1, jb = (quad & 1) * 16;     // quad 0,1 -> d 0..31; 2,3 -> d 32..63
    unsigned int* dst = reinterpret_cast<unsigned int*>(ebf2 + h * (K * 32) + k * 32 + jb);
    *reinterpret_cast<uint4*>(dst)     = uint4{pk[0], pk[1], pk[2], pk[3]};
    *reinterpret_cast<uint4*>(dst + 4) = uint4{pk[4], pk[5], pk[6], pk[7]};
}

// ---- main: 1024 blocks x 512 threads; 128 px/block; codes split across 8 waves.
__global__ __launch_bounds__(512, 4) void vq_main(const float* __restrict__ latents,
                                                  const float* __restrict__ emb,
                                                  const float* __restrict__ e2,
                                                  const unsigned short* __restrict__ ebf2,
                                                  float* __restrict__ out,
                                                  float* __restrict__ partials) {
    __shared__ unsigned short xbf[PXB * D];      // 16KB, row=pixel, XOR-swizzled
    __shared__ unsigned int   kred[8][PXB];      // 4KB  per-wave best key
    __shared__ int            inds[PXB];         // 512B
    __shared__ float          wsum[8];           // ||x||^2 partials per wave
    __shared__ float          ssum[2];           // best-score partials

    const int t    = threadIdx.x;
    const int lane = t & 63, w = t >> 6;         // 8 waves
    const int blk  = blockIdx.x;
    const int b    = blk >> 5, hw0 = (blk & 31) * PXB;
    const int r15  = lane & 15, g = lane >> 4;

    // ---- stage x: thread t owns pixel px, dims [dbase, dbase+16). HBM coalesced.
    const int px = t & 127;
    const int dbase = (t >> 7) * 16;
    const float* __restrict__ xg = latents + (size_t)b * D * HW + hw0 + px;
    float xv[16];
    #pragma unroll
    for (int j = 0; j < 16; ++j) xv[j] = xg[(size_t)(dbase + j) * HW];

    // ---- this wave's codebook slice -> VGPRs (L2/L3-resident).
    // Wave w owns codes [w*64, w*64+64) = 4 MFMA tiles; A-frag row=r15, k-chunk=g.
    short8v A0[4], A1[4];
    f32x4   EI[4];
    const char* eb = reinterpret_cast<const char*>(ebf2);
    #pragma unroll
    for (int tt = 0; tt < 4; ++tt) {
        int code = w * 64 + tt * 16 + r15;
        A0[tt] = *reinterpret_cast<const short8v*>(eb + (size_t)code * 64 + g * 16);
        A1[tt] = *reinterpret_cast<const short8v*>(eb + (size_t)(K * 64) + (size_t)code * 64 + g * 16);
        EI[tt] = *reinterpret_cast<const f32x4*>(e2 + w * 64 + tt * 16 + g * 4);
    }

    // ---- ||x||^2 partial: reduce this thread's slice across the wave now;
    // xv dies after the pack below (loss needs no x in the epilogue).
    {
        float a0 = 0.f, a1 = 0.f;
        #pragma unroll
        for (int j = 0; j < 16; j += 2) {
            a0 = fmaf(xv[j], xv[j], a0);
            a1 = fmaf(xv[j + 1], xv[j + 1], a1);
        }
        float x2 = a0 + a1;
        #pragma unroll
        for (int off = 32; off > 0; off >>= 1) x2 += __shfl_down(x2, off, 64);
        if (lane == 0) wsum[w] = x2;
    }

    // ---- pack x to bf16, write swizzled (row=px): 2x ds_write_b128 per thread.
    char* xb_c = reinterpret_cast<char*>(xbf);
    {
        const int pswz = (px & 7) << 4;
        #pragma unroll
        for (int ch = 0; ch < 2; ++ch) {
            unsigned int pk[4];
            #pragma unroll
            for (int q = 0; q < 4; ++q) {
                int j = ch * 8 + q * 2;
                pk[q] = (unsigned int)f2bf(xv[j]) | ((unsigned int)f2bf(xv[j + 1]) << 16);
            }
            int col = dbase * 2 + ch * 16;
            *reinterpret_cast<uint4*>(xb_c + px * 128 + (col ^ pswz)) = uint4{pk[0], pk[1], pk[2], pk[3]};
        }
    }
    __syncthreads();

    // ---- k-loop: wave scans all 8 pixel-tiles against its 64 codes.
    const unsigned lcbase = (unsigned)(g * 4);
    #pragma unroll
    for (int pt = 0; pt < 8; ++pt) {
        const int P = pt * 16 + r15;
        const int sw = (P & 7) << 4;
        short8v b0 = *reinterpret_cast<const short8v*>(xb_c + P * 128 + ((g * 16)      ^ sw));
        short8v b1 = *reinterpret_cast<const short8v*>(xb_c + P * 128 + ((g * 16 + 64) ^ sw));
        unsigned best = 0xFFFFFFFFu;
        #pragma unroll
        for (int tt = 0; tt < 4; ++tt) {
            f32x4 c = EI[tt];                    // C-in = e2 => D = score
            c = __builtin_amdgcn_mfma_f32_16x16x32_bf16(A0[tt], b0, c, 0, 0, 0);
            c = __builtin_amdgcn_mfma_f32_16x16x32_bf16(A1[tt], b1, c, 0, 0, 0);
            #pragma unroll
            for (int el = 0; el < 4; ++el) {
                // |score| < 0.5 => iv in (0, 2^21); key = iv<<9 | code (lex min).
                int iv = (int)fmaf(c[el], 2097152.0f, 1048576.0f);
                unsigned key = ((unsigned)iv << 9) | (lcbase + (unsigned)(tt * 16 + el));
                best = min(best, key);
            }
        }
        #pragma unroll
        for (int off = 16; off < 64; off <<= 1)  // cross-g reduce (same pixel P)
            best = min(best, (unsigned)__shfl_xor((int)best, off, 64));
        if (g == 0) kred[w][P] = best + ((unsigned)w << 6);  // globalize code bits
    }
    __syncthreads();

    // ---- cross-wave argmin + score-part of the loss (threads 0..127).
    if (t < PXB) {
        unsigned key = kred[0][t];
        #pragma unroll
        for (int wv = 1; wv < 8; ++wv) key = min(key, kred[wv][t]);
        inds[t] = (int)(key & 511u);
        float sq = ((float)(int)(key >> 9) - 1048576.0f) * (1.0f / 2097152.0f);
        #pragma unroll
        for (int off = 32; off > 0; off >>= 1) sq += __shfl_down(sq, off, 64);
        if (lane == 0) ssum[w] = sq;
    }
    __syncthreads();

    // ---- epilogue: gather chosen code fp32 (L2-resident), write out.
    const int ind = inds[px];
    const float4* __restrict__ q4 = reinterpret_cast<const float4*>(emb + ind * D + dbase);
    float* __restrict__ og = out + (size_t)b * D * HW + hw0 + px;
    #pragma unroll
    for (int i = 0; i < 4; ++i) {
        float4 q = q4[i];
        int j = 4 * i;
        og[(size_t)(dbase + j + 0) * HW] = q.x;
        og[(size_t)(dbase + j + 1) * HW] = q.y;
        og[(size_t)(dbase + j + 2) * HW] = q.z;
        og[(size_t)(dbase + j + 3) * HW] = q.w;
    }
    if (t == 0) {
        float s = ssum[0] + ssum[1];
        #pragma unroll
        for (int i = 0; i < 8; ++i) s += wsum[i];
        partials[blk] = s;                       // sum_px (||x||^2 + best_score)
    }
}

__global__ __launch_bounds__(1024) void vq_finalize(const float* __restrict__ partials,
                                                    float* __restrict__ out_loss) {
    int t = threadIdx.x;
    float v = partials[t];                       // 1024 partials, one block
    #pragma unroll
    for (int off = 32; off > 0; off >>= 1) v += __shfl_down(v, off, 64);
    __shared__ float s16[16];
    if ((t & 63) == 0) s16[t >> 6] = v;
    __syncthreads();
    if (t == 0) {
        float tot = 0.f;
        #pragma unroll
        for (int i = 0; i < 16; ++i) tot += s16[i];
        out_loss[0] = 1.25f * tot / (float)NELEM;   // beta*commit + embed (equal values)
    }
}

extern "C" void kernel_launch(void* const* d_in, const int* in_sizes, int n_in,
                              void* d_out, int out_size, void* d_ws, size_t ws_size,
                              hipStream_t stream) {
    const float* latents = (const float*)d_in[0];
    const float* emb     = (const float*)d_in[1];
    float* out = (float*)d_out;
    float* ws  = (float*)d_ws;

    float*          part = ws;                               // [0..1024)
    float*          e2   = ws + 1024;                        // [1024..1536)
    unsigned short* ebf2 = (unsigned short*)(ws + 1536);     // 64KB

    vq_prep<<<32, 256, 0, stream>>>(emb, e2, ebf2);
    vq_main<<<NBLK, 512, 0, stream>>>(latents, emb, e2, ebf2, out, part);
    vq_finalize<<<1, 1024, 0, stream>>>(part, out + NELEM);
}

// Round 6
// 29.903 us; speedup vs baseline: 1.5231x; 1.1233x over previous
//
#include <hip/hip_runtime.h>

// VQ codebook search via bf16 MFMA — pipelined 2-tile, codebook-in-VGPR.
// latents: [32, 64, 64, 64] = [b, d, h, w] fp32
// emb:     [512, 64] fp32
// out:     8388608 floats quantized (b,d,h,w) + 1 float vq_loss
//
// score[n,k] = ||e_k||^2 - 2 x_n.e_k  (+16 bias), MFMA 16x16x32:
//   A = bf16(-2E) in VGPRs (wave w owns codes [w*64,w*64+64)),
//   B = bf16(X) from XOR-swizzled LDS, C-init = e2+16  =>  D = biased score > 0.
// argmin via u32 key = (float_bits(score) & ~511) | code  (positive floats:
//   bits are order-monotone; low 9 bits carry the code; min = lex order).
// loss identity: ||q-x||^2 = ||x||^2 + (score-16)  -> x dies after staging.
//
// Pipelining: each block does 2 px-tiles; tile1 global loads issue before
// tile0's k-loop and barriers are lgkm-only (raw s_barrier), so the loads
// stay in flight across them (T14 async-stage; __syncthreads would vmcnt(0)).
//
// ws layout (floats): [0..512) per-block loss partials; [512..1024) e2;
//   ws+1024: ebf2 = bf16(-2E) as [2 halves][512 codes][32 d], 64KB.

typedef short short8v __attribute__((ext_vector_type(8)));
typedef float f32x4   __attribute__((ext_vector_type(4)));

constexpr int K = 512;
constexpr int D = 64;
constexpr int HW = 4096;
constexpr int NPIX = 32 * HW;
constexpr long long NELEM = (long long)NPIX * D;
constexpr int PXT = 128;                 // pixels per tile
constexpr int NBLK = 512;                // blocks; 2 tiles each = 1024 tiles

__device__ inline unsigned short f2bf(float f) {   // RNE float->bf16 bits
    unsigned int u = __builtin_bit_cast(unsigned int, f);
    u += 0x7fffu + ((u >> 16) & 1u);
    return (unsigned short)(u >> 16);
}

__device__ inline unsigned umin(unsigned a, unsigned b) { return a < b ? a : b; }

// lgkm-only barrier: LDS producers visible, global loads stay in flight.
__device__ inline void lbar() {
    asm volatile("s_waitcnt lgkmcnt(0)" ::: "memory");
    __builtin_amdgcn_sched_barrier(0);
    __builtin_amdgcn_s_barrier();
}

// ---- prep: e2[k] = ||e_k||^2 fp32; ebf2[h][k][j] = bf16(-2*emb[k][h*32+j]).
__global__ __launch_bounds__(256) void vq_prep(const float* __restrict__ emb,
                                               float* __restrict__ e2,
                                               unsigned short* __restrict__ ebf2) {
    int tid = blockIdx.x * 256 + threadIdx.x;    // 0..8191 = k*4 + quad (16 d's each)
    int k = tid >> 2, quad = tid & 3;
    const float4* src = reinterpret_cast<const float4*>(emb + k * D + quad * 16);
    unsigned int pk[8];
    float s = 0.f;
    #pragma unroll
    for (int i = 0; i < 4; ++i) {
        float4 v = src[i];
        s = fmaf(v.x, v.x, fmaf(v.y, v.y, fmaf(v.z, v.z, fmaf(v.w, v.w, s))));
        pk[2*i]   = (unsigned int)f2bf(-2.f * v.x) | ((unsigned int)f2bf(-2.f * v.y) << 16);
        pk[2*i+1] = (unsigned int)f2bf(-2.f * v.z) | ((unsigned int)f2bf(-2.f * v.w) << 16);
    }
    s += __shfl_xor(s, 1, 64);                   // reduce over the 4 quads of row k
    s += __shfl_xor(s, 2, 64);
    if (quad == 0) e2[k] = s;
    int h = quad >> 1, jb = (quad & 1) * 16;
    unsigned int* dst = reinterpret_cast<unsigned int*>(ebf2 + h * (K * 32) + k * 32 + jb);
    *reinterpret_cast<uint4*>(dst)     = uint4{pk[0], pk[1], pk[2], pk[3]};
    *reinterpret_cast<uint4*>(dst + 4) = uint4{pk[4], pk[5], pk[6], pk[7]};
}

// pack one tile's x slice to bf16 LDS (XOR-swizzled); returns ||x||^2 partial.
__device__ inline float pack_tile(unsigned short* xbf, int px, int dbase,
                                  const float xv[16]) {
    char* c = reinterpret_cast<char*>(xbf);
    const int pswz = (px & 7) << 4;
    #pragma unroll
    for (int ch = 0; ch < 2; ++ch) {
        unsigned int pk[4];
        #pragma unroll
        for (int q = 0; q < 4; ++q) {
            int j = ch * 8 + q * 2;
            pk[q] = (unsigned int)f2bf(xv[j]) | ((unsigned int)f2bf(xv[j + 1]) << 16);
        }
        int col = dbase * 2 + ch * 16;
        *reinterpret_cast<uint4*>(c + px * 128 + (col ^ pswz)) = uint4{pk[0], pk[1], pk[2], pk[3]};
    }
    float a0 = 0.f, a1 = 0.f;
    #pragma unroll
    for (int j = 0; j < 16; j += 2) {
        a0 = fmaf(xv[j], xv[j], a0);
        a1 = fmaf(xv[j + 1], xv[j + 1], a1);
    }
    return a0 + a1;
}

// scan 8 pixel-tiles vs this wave's 64 codes; per-wave best keys -> kred.
__device__ inline void kloop_tile(const unsigned short* xbf,
                                  const short8v A0[4], const short8v A1[4],
                                  const f32x4 EI[4],
                                  int w, int r15, int g,
                                  unsigned int (*kred)[PXT]) {
    const char* c = reinterpret_cast<const char*>(xbf);
    const unsigned lc = (unsigned)(g * 4);
    #pragma unroll
    for (int pt = 0; pt < 8; ++pt) {
        const int P = pt * 16 + r15;
        const int sw = (P & 7) << 4;
        short8v b0 = *reinterpret_cast<const short8v*>(c + P * 128 + ((g * 16)      ^ sw));
        short8v b1 = *reinterpret_cast<const short8v*>(c + P * 128 + ((g * 16 + 64) ^ sw));
        unsigned best = 0xFFFFFFFFu;
        #pragma unroll
        for (int tt = 0; tt < 4; ++tt) {
            f32x4 cc = EI[tt];                   // C-in = e2+16 => D = biased score
            cc = __builtin_amdgcn_mfma_f32_16x16x32_bf16(A0[tt], b0, cc, 0, 0, 0);
            cc = __builtin_amdgcn_mfma_f32_16x16x32_bf16(A1[tt], b1, cc, 0, 0, 0);
            #pragma unroll
            for (int el = 0; el < 4; ++el) {     // positive float => bits monotone
                unsigned u = __builtin_bit_cast(unsigned, cc[el]);
                best = umin(best, (u & 0xFFFFFE00u) | (lc + (unsigned)(tt * 16 + el)));
            }
        }
        #pragma unroll
        for (int off = 16; off < 64; off <<= 1)  // cross-g reduce (same pixel P)
            best = umin(best, (unsigned)__shfl_xor((int)best, off, 64));
        if (g == 0) kred[w][P] = best + ((unsigned)w << 6);  // globalize code bits
    }
}

// gather chosen fp32 code and write output slice (stores drain async).
__device__ inline void epi_tile(const float* __restrict__ emb, const int* inds,
                                float* __restrict__ out, int b, int hw0,
                                int px, int dbase) {
    const int ind = inds[px];
    const float4* __restrict__ q4 = reinterpret_cast<const float4*>(emb + ind * D + dbase);
    float* __restrict__ og = out + (size_t)b * D * HW + hw0 + px;
    #pragma unroll
    for (int i = 0; i < 4; ++i) {
        float4 q = q4[i];
        int j = 4 * i;
        og[(size_t)(dbase + j + 0) * HW] = q.x;
        og[(size_t)(dbase + j + 1) * HW] = q.y;
        og[(size_t)(dbase + j + 2) * HW] = q.z;
        og[(size_t)(dbase + j + 3) * HW] = q.w;
    }
}

// ---- main: 512 blocks x 512 threads; two pipelined 128-px tiles per block.
__global__ __launch_bounds__(512, 4) void vq_main(const float* __restrict__ latents,
                                                  const float* __restrict__ emb,
                                                  const float* __restrict__ e2,
                                                  const unsigned short* __restrict__ ebf2,
                                                  float* __restrict__ out,
                                                  float* __restrict__ partials) {
    __shared__ unsigned short xbf0[PXT * D];     // 16KB tile0 B-operand
    __shared__ unsigned short xbf1[PXT * D];     // 16KB tile1 B-operand
    __shared__ unsigned int   kred[8][PXT];      // 4KB per-wave best keys
    __shared__ int            inds0[PXT], inds1[PXT];
    __shared__ float          ssum0[2], ssum1[2], wsum[8];

    const int t    = threadIdx.x;
    const int lane = t & 63, w = t >> 6;         // 8 waves
    const int r15  = lane & 15, g = lane >> 4;
    const int px   = t & 127;
    const int dbase = (t >> 7) * 16;

    const int T0 = blockIdx.x * 2, T1 = T0 + 1;  // 32 tiles per batch image
    const int b0 = T0 >> 5, hw00 = (T0 & 31) * PXT;
    const int b1 = T1 >> 5, hw01 = (T1 & 31) * PXT;

    // ---- stage tile0 x (HBM/L3, coalesced 256B per wave-instr).
    const float* __restrict__ xg0 = latents + (size_t)b0 * D * HW + hw00 + px;
    float xv0[16];
    #pragma unroll
    for (int j = 0; j < 16; ++j) xv0[j] = xg0[(size_t)(dbase + j) * HW];

    // ---- this wave's codebook slice -> VGPRs; fold +16 bias into C-init.
    short8v A0[4], A1[4];
    f32x4   EI[4];
    const char* eb = reinterpret_cast<const char*>(ebf2);
    #pragma unroll
    for (int tt = 0; tt < 4; ++tt) {
        int code = w * 64 + tt * 16 + r15;
        A0[tt] = *reinterpret_cast<const short8v*>(eb + (size_t)code * 64 + g * 16);
        A1[tt] = *reinterpret_cast<const short8v*>(eb + (size_t)(K * 64) + (size_t)code * 64 + g * 16);
        f32x4 ev = *reinterpret_cast<const f32x4*>(e2 + w * 64 + tt * 16 + g * 4);
        EI[tt] = ev + 16.0f;
    }

    float x2 = pack_tile(xbf0, px, dbase, xv0);  // xv0 dies here

    // ---- issue tile1 loads NOW; they fly across the light barriers + kloop0.
    const float* __restrict__ xg1 = latents + (size_t)b1 * D * HW + hw01 + px;
    float xv1[16];
    #pragma unroll
    for (int j = 0; j < 16; ++j) xv1[j] = xg1[(size_t)(dbase + j) * HW];

    lbar();                                      // xbf0 visible; xv1 in flight

    kloop_tile(xbf0, A0, A1, EI, w, r15, g, kred);

    lbar();                                      // kred(tile0) visible

    if (t < PXT) {                               // cross-wave argmin tile0 + score sum
        unsigned key = kred[0][t];
        #pragma unroll
        for (int wv = 1; wv < 8; ++wv) key = umin(key, kred[wv][t]);
        inds0[t] = (int)(key & 511u);
        float sq = __builtin_bit_cast(float, key & 0xFFFFFE00u) - 16.0f;
        #pragma unroll
        for (int off = 32; off > 0; off >>= 1) sq += __shfl_down(sq, off, 64);
        if (lane == 0) ssum0[w] = sq;
    }
    x2 += pack_tile(xbf1, px, dbase, xv1);       // waits vmcnt for xv1 here

    lbar();                                      // inds0 + xbf1 visible; kred free

    epi_tile(emb, inds0, out, b0, hw00, px, dbase);   // stores drain under kloop1

    kloop_tile(xbf1, A0, A1, EI, w, r15, g, kred);

    lbar();                                      // kred(tile1) visible

    if (t < PXT) {
        unsigned key = kred[0][t];
        #pragma unroll
        for (int wv = 1; wv < 8; ++wv) key = umin(key, kred[wv][t]);
        inds1[t] = (int)(key & 511u);
        float sq = __builtin_bit_cast(float, key & 0xFFFFFE00u) - 16.0f;
        #pragma unroll
        for (int off = 32; off > 0; off >>= 1) sq += __shfl_down(sq, off, 64);
        if (lane == 0) ssum1[w] = sq;
    }
    #pragma unroll
    for (int off = 32; off > 0; off >>= 1) x2 += __shfl_down(x2, off, 64);
    if (lane == 0) wsum[w] = x2;

    lbar();                                      // inds1 + ssum* + wsum visible

    epi_tile(emb, inds1, out, b1, hw01, px, dbase);

    if (t == 0) {
        float s = ssum0[0] + ssum0[1] + ssum1[0] + ssum1[1];
        #pragma unroll
        for (int i = 0; i < 8; ++i) s += wsum[i];
        partials[blockIdx.x] = s;                // sum_px (||x||^2 + best_score)
    }
}

__global__ __launch_bounds__(512) void vq_finalize(const float* __restrict__ partials,
                                                   float* __restrict__ out_loss) {
    int t = threadIdx.x;
    float v = partials[t];                       // 512 partials, one block
    #pragma unroll
    for (int off = 32; off > 0; off >>= 1) v += __shfl_down(v, off, 64);
    __shared__ float s8[8];
    if ((t & 63) == 0) s8[t >> 6] = v;
    __syncthreads();
    if (t == 0) {
        float tot = 0.f;
        #pragma unroll
        for (int i = 0; i < 8; ++i) tot += s8[i];
        out_loss[0] = 1.25f * tot / (float)NELEM;   // beta*commit + embed (equal values)
    }
}

extern "C" void kernel_launch(void* const* d_in, const int* in_sizes, int n_in,
                              void* d_out, int out_size, void* d_ws, size_t ws_size,
                              hipStream_t stream) {
    const float* latents = (const float*)d_in[0];
    const float* emb     = (const float*)d_in[1];
    float* out = (float*)d_out;
    float* ws  = (float*)d_ws;

    float*          part = ws;                               // [0..512)
    float*          e2   = ws + 512;                         // [512..1024)
    unsigned short* ebf2 = (unsigned short*)(ws + 1024);     // 64KB

    vq_prep<<<32, 256, 0, stream>>>(emb, e2, ebf2);
    vq_main<<<NBLK, 512, 0, stream>>>(latents, emb, e2, ebf2, out, part);
    vq_finalize<<<1, 512, 0, stream>>>(part, out + NELEM);
}